// Round 1
// baseline (1423.499 us; speedup 1.0000x reference)
//
#include <hip/hip_runtime.h>
#include <cstdint>
#include <cstddef>

#define B_    64
#define N_    4096
#define D_    1024
#define DIN   2048
#define DHID  4096
#define OUT_N 1000
#define EPSF  1e-6f

// ---------------------------------------------------------------------------
// Kernel A: encoder row norms + copy enc into cat[:, 0:1024]
// grid 64, block 256 (one float4 per thread)
// ---------------------------------------------------------------------------
__global__ void k_enc(const float* __restrict__ enc, float* __restrict__ cat,
                      float* __restrict__ inv_enc) {
  int b = blockIdx.x, tid = threadIdx.x;
  const float4* er = (const float4*)(enc + (size_t)b * D_);
  float4 v = er[tid];
  float ss = v.x*v.x + v.y*v.y + v.z*v.z + v.w*v.w;
  #pragma unroll
  for (int o = 32; o > 0; o >>= 1) ss += __shfl_xor(ss, o, 64);
  __shared__ float sb[4];
  if ((tid & 63) == 0) sb[tid >> 6] = ss;
  __syncthreads();
  if (tid == 0) {
    float t = sb[0] + sb[1] + sb[2] + sb[3];
    inv_enc[b] = 1.0f / fmaxf(sqrtf(t), EPSF);
  }
  ((float4*)(cat + (size_t)b * DIN))[tid] = v;
}

// ---------------------------------------------------------------------------
// Kernel B: z[b,n] = cos(enc[b], mem[b,n])   (the 1.07 GB HBM-bound pass)
// one wave per memory row; 4 waves/block; grid = B*N/4 = 65536
// ---------------------------------------------------------------------------
__global__ void k_cos(const float* __restrict__ enc, const float* __restrict__ mem,
                      const float* __restrict__ inv_enc, float* __restrict__ z) {
  int tid  = threadIdx.x;
  int lane = tid & 63;
  int r    = blockIdx.x * 4 + (tid >> 6);   // global row in [0, B*N)
  int b    = r >> 12;                        // r / 4096
  const float4* mr = (const float4*)mem + (size_t)r * 256;
  const float4* er = (const float4*)enc + (size_t)b * 256;
  float dot = 0.f, ss = 0.f;
  #pragma unroll
  for (int j = 0; j < 4; ++j) {
    float4 m = mr[j * 64 + lane];   // each instruction covers contiguous 1 KiB
    float4 e = er[j * 64 + lane];
    dot += e.x*m.x + e.y*m.y + e.z*m.z + e.w*m.w;
    ss  += m.x*m.x + m.y*m.y + m.z*m.z + m.w*m.w;
  }
  #pragma unroll
  for (int o = 32; o > 0; o >>= 1) {
    dot += __shfl_xor(dot, o, 64);
    ss  += __shfl_xor(ss,  o, 64);
  }
  if (lane == 0) z[r] = dot * inv_enc[b] / fmaxf(sqrtf(ss), EPSF);
}

// ---------------------------------------------------------------------------
// Kernel C: sparsemax over each row of z [64, 4096] via bisection on tau,
// exact refinement, then compaction of nonzeros into (idx, w) lists.
// grid 64, block 256 (16 elements per thread, kept in registers)
// ---------------------------------------------------------------------------
__global__ void k_sparsemax(const float* __restrict__ z, int* __restrict__ idxl,
                            float* __restrict__ wl, int* __restrict__ cnt) {
  int b = blockIdx.x, tid = threadIdx.x;
  const float* zr = z + (size_t)b * N_;
  float zv[16];
  #pragma unroll
  for (int j = 0; j < 16; ++j) zv[j] = zr[j * 256 + tid];

  __shared__ float sb[4];
  __shared__ float sb2[4];

  // row max
  float mx = -1e30f;
  #pragma unroll
  for (int j = 0; j < 16; ++j) mx = fmaxf(mx, zv[j]);
  #pragma unroll
  for (int o = 32; o > 0; o >>= 1) mx = fmaxf(mx, __shfl_xor(mx, o, 64));
  if ((tid & 63) == 0) sb[tid >> 6] = mx;
  __syncthreads();
  mx = fmaxf(fmaxf(sb[0], sb[1]), fmaxf(sb[2], sb[3]));
  __syncthreads();

  // bisection: f(lo) >= 1 > f(hi), root = tau with sum(max(z-tau,0)) = 1
  float lo = mx - 1.0f, hi = mx;
  for (int it = 0; it < 40; ++it) {
    float mid = 0.5f * (lo + hi);
    float s = 0.f;
    #pragma unroll
    for (int j = 0; j < 16; ++j) {
      float d = zv[j] - mid;
      s += (d > 0.f) ? d : 0.f;
    }
    #pragma unroll
    for (int o = 32; o > 0; o >>= 1) s += __shfl_xor(s, o, 64);
    if ((tid & 63) == 0) sb[tid >> 6] = s;
    __syncthreads();
    s = sb[0] + sb[1] + sb[2] + sb[3];
    __syncthreads();
    if (s >= 1.0f) lo = mid; else hi = mid;   // uniform branch (s broadcast)
  }
  float mid = 0.5f * (lo + hi);

  // exact refinement: K = |{z > mid}|, tau = (sum_support - 1) / K
  float c = 0.f, s = 0.f;
  #pragma unroll
  for (int j = 0; j < 16; ++j) {
    if (zv[j] > mid) { c += 1.0f; s += zv[j]; }
  }
  #pragma unroll
  for (int o = 32; o > 0; o >>= 1) {
    c += __shfl_xor(c, o, 64);
    s += __shfl_xor(s, o, 64);
  }
  if ((tid & 63) == 0) { sb[tid >> 6] = c; sb2[tid >> 6] = s; }
  __syncthreads();
  c = sb[0] + sb[1] + sb[2] + sb[3];
  s = sb2[0] + sb2[1] + sb2[2] + sb2[3];
  float tau = (s - 1.0f) / fmaxf(c, 1.0f);

  // compact nonzeros (order irrelevant for the weighted sum)
  __shared__ int scnt;
  if (tid == 0) scnt = 0;
  __syncthreads();
  #pragma unroll
  for (int j = 0; j < 16; ++j) {
    float w = zv[j] - tau;
    if (w > 0.f) {
      int p = atomicAdd(&scnt, 1);
      idxl[(size_t)b * N_ + p] = j * 256 + tid;
      wl[(size_t)b * N_ + p]   = w;
    }
  }
  __syncthreads();
  if (tid == 0) cnt[b] = scnt;
}

// ---------------------------------------------------------------------------
// Kernel D: memory_vector[b,:] = sum over support of w * mem[b,n,:]
// grid 64, block 256 (one float4 of the 1024-dim accumulator per thread)
// Only reads ~nnz (~100) rows per batch -> ~26 MB total instead of 1.07 GB.
// ---------------------------------------------------------------------------
__global__ void k_memvec(const float* __restrict__ mem, const int* __restrict__ idxl,
                         const float* __restrict__ wl, const int* __restrict__ cnt,
                         float* __restrict__ cat) {
  int b = blockIdx.x, tid = threadIdx.x;
  int nnz = cnt[b];
  __shared__ int   sidx[256];
  __shared__ float sw[256];
  float4 acc = make_float4(0.f, 0.f, 0.f, 0.f);
  const float4* mb = (const float4*)mem + (size_t)b * N_ * 256;
  for (int c0 = 0; c0 < nnz; c0 += 256) {
    int c = nnz - c0; if (c > 256) c = 256;
    if (tid < c) {
      sidx[tid] = idxl[(size_t)b * N_ + c0 + tid];
      sw[tid]   = wl[(size_t)b * N_ + c0 + tid];
    }
    __syncthreads();
    #pragma unroll 4
    for (int i = 0; i < c; ++i) {
      float  w = sw[i];
      float4 r = mb[(size_t)sidx[i] * 256 + tid];
      acc.x += w * r.x; acc.y += w * r.y; acc.z += w * r.z; acc.w += w * r.w;
    }
    __syncthreads();
  }
  ((float4*)(cat + (size_t)b * DIN + D_))[tid] = acc;
}

// ---------------------------------------------------------------------------
// Kernel E: GEMM1 partials: hp[kt][m][n] = sum_{k in slice kt} cat[m,k]*W1[n,k]
// grid (64 n-tiles, 4 k-slices), block 256. BM=BN=64, BK=16, K-slice 512.
// ---------------------------------------------------------------------------
__global__ void k_gemm1(const float* __restrict__ X, const float* __restrict__ W,
                        float* __restrict__ hp) {
  int nt = blockIdx.x, kt = blockIdx.y, tid = threadIdx.x;
  __shared__ float Xs[16][68];
  __shared__ float Ws[16][68];
  int row = tid >> 2, c4 = (tid & 3) * 4;     // loader coords
  int tm = (tid & 15) * 4, tn = (tid >> 4) * 4; // compute coords (4x4 tile)
  float acc[4][4] = {};
  const float* Xp = X + (size_t)row * DIN + c4;
  const float* Wp = W + ((size_t)nt * 64 + row) * DIN + c4;
  int kend = kt * 512 + 512;
  for (int k0 = kt * 512; k0 < kend; k0 += 16) {
    float4 xv = *(const float4*)(Xp + k0);
    float4 wv = *(const float4*)(Wp + k0);
    __syncthreads();
    Xs[c4+0][row] = xv.x; Xs[c4+1][row] = xv.y; Xs[c4+2][row] = xv.z; Xs[c4+3][row] = xv.w;
    Ws[c4+0][row] = wv.x; Ws[c4+1][row] = wv.y; Ws[c4+2][row] = wv.z; Ws[c4+3][row] = wv.w;
    __syncthreads();
    #pragma unroll
    for (int kk = 0; kk < 16; ++kk) {
      float a0 = Xs[kk][tm+0], a1 = Xs[kk][tm+1], a2 = Xs[kk][tm+2], a3 = Xs[kk][tm+3];
      float b0 = Ws[kk][tn+0], b1 = Ws[kk][tn+1], b2 = Ws[kk][tn+2], b3 = Ws[kk][tn+3];
      acc[0][0] += a0*b0; acc[0][1] += a0*b1; acc[0][2] += a0*b2; acc[0][3] += a0*b3;
      acc[1][0] += a1*b0; acc[1][1] += a1*b1; acc[1][2] += a1*b2; acc[1][3] += a1*b3;
      acc[2][0] += a2*b0; acc[2][1] += a2*b1; acc[2][2] += a2*b2; acc[2][3] += a2*b3;
      acc[3][0] += a3*b0; acc[3][1] += a3*b1; acc[3][2] += a3*b2; acc[3][3] += a3*b3;
    }
  }
  float* o = hp + ((size_t)kt * 64 + tm) * DHID + nt * 64 + tn;
  #pragma unroll
  for (int i = 0; i < 4; ++i)
    *(float4*)(o + (size_t)i * DHID) = make_float4(acc[i][0], acc[i][1], acc[i][2], acc[i][3]);
}

// ---------------------------------------------------------------------------
// Kernel F: GEMM2 partials with fused bias1+ReLU on the X load.
// X[m,k] = relu(b1[k] + sum_p hp[p][m][k]);  op[kt][m][n] = partial X @ W2^T
// grid (16 n-tiles, 16 k-slices), block 256. K-slice 256.
// ---------------------------------------------------------------------------
__global__ void k_gemm2(const float* __restrict__ hp, const float* __restrict__ b1p,
                        const float* __restrict__ W2, float* __restrict__ op) {
  int nt = blockIdx.x, kt = blockIdx.y, tid = threadIdx.x;
  __shared__ float Xs[16][68];
  __shared__ float Ws[16][68];
  int row = tid >> 2, c4 = (tid & 3) * 4;
  int tm = (tid & 15) * 4, tn = (tid >> 4) * 4;
  int nbase = nt * 64;
  float acc[4][4] = {};
  int kend = kt * 256 + 256;
  for (int k0 = kt * 256; k0 < kend; k0 += 16) {
    int k = k0 + c4;
    float4 xv = *(const float4*)(b1p + k);
    #pragma unroll
    for (int p = 0; p < 4; ++p) {
      float4 h = *(const float4*)(hp + ((size_t)p * 64 + row) * DHID + k);
      xv.x += h.x; xv.y += h.y; xv.z += h.z; xv.w += h.w;
    }
    xv.x = fmaxf(xv.x, 0.f); xv.y = fmaxf(xv.y, 0.f);
    xv.z = fmaxf(xv.z, 0.f); xv.w = fmaxf(xv.w, 0.f);
    int n = nbase + row;
    float4 wv = make_float4(0.f, 0.f, 0.f, 0.f);
    if (n < OUT_N) wv = *(const float4*)(W2 + (size_t)n * DHID + k);
    __syncthreads();
    Xs[c4+0][row] = xv.x; Xs[c4+1][row] = xv.y; Xs[c4+2][row] = xv.z; Xs[c4+3][row] = xv.w;
    Ws[c4+0][row] = wv.x; Ws[c4+1][row] = wv.y; Ws[c4+2][row] = wv.z; Ws[c4+3][row] = wv.w;
    __syncthreads();
    #pragma unroll
    for (int kk = 0; kk < 16; ++kk) {
      float a0 = Xs[kk][tm+0], a1 = Xs[kk][tm+1], a2 = Xs[kk][tm+2], a3 = Xs[kk][tm+3];
      float b0 = Ws[kk][tn+0], b1 = Ws[kk][tn+1], b2 = Ws[kk][tn+2], b3 = Ws[kk][tn+3];
      acc[0][0] += a0*b0; acc[0][1] += a0*b1; acc[0][2] += a0*b2; acc[0][3] += a0*b3;
      acc[1][0] += a1*b0; acc[1][1] += a1*b1; acc[1][2] += a1*b2; acc[1][3] += a1*b3;
      acc[2][0] += a2*b0; acc[2][1] += a2*b1; acc[2][2] += a2*b2; acc[2][3] += a2*b3;
      acc[3][0] += a3*b0; acc[3][1] += a3*b1; acc[3][2] += a3*b2; acc[3][3] += a3*b3;
    }
  }
  // op layout: [16][64][1024] (N padded to 1024; cols >= 1000 unused)
  float* o = op + ((size_t)kt * 64 + tm) * 1024 + nbase + tn;
  #pragma unroll
  for (int i = 0; i < 4; ++i)
    *(float4*)(o + (size_t)i * 1024) = make_float4(acc[i][0], acc[i][1], acc[i][2], acc[i][3]);
}

// ---------------------------------------------------------------------------
// Kernel G: out[b,o] = b2[o] + sum_kt op[kt][b][o]
// grid (4, 64), block 256
// ---------------------------------------------------------------------------
__global__ void k_out(const float* __restrict__ op, const float* __restrict__ b2p,
                      float* __restrict__ out) {
  int o = blockIdx.x * 256 + threadIdx.x;
  int b = blockIdx.y;
  if (o >= OUT_N) return;
  float s = b2p[o];
  #pragma unroll
  for (int kt = 0; kt < 16; ++kt) s += op[((size_t)kt * 64 + b) * 1024 + o];
  out[(size_t)b * OUT_N + o] = s;
}

// ---------------------------------------------------------------------------
extern "C" void kernel_launch(void* const* d_in, const int* in_sizes, int n_in,
                              void* d_out, int out_size, void* d_ws, size_t ws_size,
                              hipStream_t stream) {
  const float* enc = (const float*)d_in[0];   // [64, 1024]
  const float* mem = (const float*)d_in[1];   // [64, 4096, 1024]
  const float* W1  = (const float*)d_in[2];   // [4096, 2048]
  const float* b1  = (const float*)d_in[3];   // [4096]
  const float* W2  = (const float*)d_in[4];   // [1000, 4096]
  const float* b2  = (const float*)d_in[5];   // [1000]
  float* out = (float*)d_out;                 // [64, 1000]

  // workspace layout (floats); everything fully written before read
  float* ws      = (float*)d_ws;
  float* inv_enc = ws;                               // 64
  int*   cnt     = (int*)(ws + 64);                  // 64
  float* z       = ws + 128;                         // 262144
  int*   idxl    = (int*)(ws + 128 + 262144);        // 262144
  float* wl      = ws + 128 + 2 * 262144;            // 262144
  float* cat     = ws + 128 + 3 * 262144;            // 131072  [64, 2048]
  float* hp      = cat + 131072;                     // 1048576 [4][64][4096]
  float* op      = hp + 1048576;                     // 1048576 [16][64][1024]

  k_enc      <<<dim3(64),      dim3(256), 0, stream>>>(enc, cat, inv_enc);
  k_cos      <<<dim3(65536),   dim3(256), 0, stream>>>(enc, mem, inv_enc, z);
  k_sparsemax<<<dim3(64),      dim3(256), 0, stream>>>(z, idxl, wl, cnt);
  k_memvec   <<<dim3(64),      dim3(256), 0, stream>>>(mem, idxl, wl, cnt, cat);
  k_gemm1    <<<dim3(64, 4),   dim3(256), 0, stream>>>(cat, W1, hp);
  k_gemm2    <<<dim3(16, 16),  dim3(256), 0, stream>>>(hp, b1, W2, op);
  k_out      <<<dim3(4, 64),   dim3(256), 0, stream>>>(op, b2, out);
}

// Round 2
// 1421.172 us; speedup vs baseline: 1.0016x; 1.0016x over previous
//
#include <hip/hip_runtime.h>
#include <cstdint>
#include <cstddef>

#define B_    64
#define N_    4096
#define D_    1024
#define DIN   2048
#define DHID  4096
#define OUT_N 1000
#define EPSF  1e-6f

// ---------------------------------------------------------------------------
// Kernel A: encoder row norms + copy enc into cat[:, 0:1024]
// grid 64, block 256 (one float4 per thread)
// ---------------------------------------------------------------------------
__global__ void k_prep(const float* __restrict__ enc, float* __restrict__ cat,
                       float* __restrict__ inv_enc) {
  int b = blockIdx.x, tid = threadIdx.x;
  const float4* er = (const float4*)(enc + (size_t)b * D_);
  float4 v = er[tid];
  float ss = v.x*v.x + v.y*v.y + v.z*v.z + v.w*v.w;
  #pragma unroll
  for (int o = 32; o > 0; o >>= 1) ss += __shfl_xor(ss, o, 64);
  __shared__ float sb[4];
  if ((tid & 63) == 0) sb[tid >> 6] = ss;
  __syncthreads();
  if (tid == 0) {
    float t = sb[0] + sb[1] + sb[2] + sb[3];
    inv_enc[b] = 1.0f / fmaxf(sqrtf(t), EPSF);
  }
  ((float4*)(cat + (size_t)b * DIN))[tid] = v;
}

// ---------------------------------------------------------------------------
// Kernel B: zraw[b,n] = dot(enc[b], mem[b,n]) / max(||mem[b,n]||, eps)
// (per-batch 1/||enc|| factor applied later in sparsemax — removes dep)
// one wave per memory row; 4 waves/block; grid = B*N/4 = 65536
// This is the 1.07 GB HBM-bound pass.
// ---------------------------------------------------------------------------
__global__ void k_cos(const float* __restrict__ enc, const float* __restrict__ mem,
                      float* __restrict__ z) {
  int tid  = threadIdx.x;
  int lane = tid & 63;
  int r    = blockIdx.x * 4 + (tid >> 6);   // global row in [0, B*N)
  int b    = r >> 12;                        // r / 4096
  const float4* mr = (const float4*)mem + (size_t)r * 256;
  const float4* er = (const float4*)enc + (size_t)b * 256;
  float dot = 0.f, ss = 0.f;
  #pragma unroll
  for (int j = 0; j < 4; ++j) {
    float4 m = mr[j * 64 + lane];   // contiguous 1 KiB per instruction
    float4 e = er[j * 64 + lane];   // L1-cached (4 KB row, same b per block)
    dot += e.x*m.x + e.y*m.y + e.z*m.z + e.w*m.w;
    ss  += m.x*m.x + m.y*m.y + m.z*m.z + m.w*m.w;
  }
  #pragma unroll
  for (int o = 32; o > 0; o >>= 1) {
    dot += __shfl_xor(dot, o, 64);
    ss  += __shfl_xor(ss,  o, 64);
  }
  if (lane == 0) {
    float inv = rsqrtf(ss);                  // ||m|| ~ 32, no eps risk; clamp anyway
    inv = fminf(inv, 1.0f / EPSF);
    z[r] = dot * inv;
  }
}

// ---------------------------------------------------------------------------
// Kernel C: sparsemax over each row of z*inv_enc [64, 4096] via bisection,
// exact refinement, then compaction of nonzeros into (idx, w) lists.
// grid 64, block 256 (16 elements per thread, kept in registers)
// ---------------------------------------------------------------------------
__global__ void k_sparsemax(const float* __restrict__ z, const float* __restrict__ inv_enc,
                            int* __restrict__ idxl, float* __restrict__ wl,
                            int* __restrict__ cnt) {
  int b = blockIdx.x, tid = threadIdx.x;
  const float* zr = z + (size_t)b * N_;
  float ie = inv_enc[b];
  float zv[16];
  #pragma unroll
  for (int j = 0; j < 16; ++j) zv[j] = zr[j * 256 + tid] * ie;

  __shared__ float sb[4];
  __shared__ float sb2[4];

  // row max
  float mx = -1e30f;
  #pragma unroll
  for (int j = 0; j < 16; ++j) mx = fmaxf(mx, zv[j]);
  #pragma unroll
  for (int o = 32; o > 0; o >>= 1) mx = fmaxf(mx, __shfl_xor(mx, o, 64));
  if ((tid & 63) == 0) sb[tid >> 6] = mx;
  __syncthreads();
  mx = fmaxf(fmaxf(sb[0], sb[1]), fmaxf(sb[2], sb[3]));
  __syncthreads();

  // bisection: f(lo) >= 1 > f(hi), root tau: sum(max(z-tau,0)) = 1
  float lo = mx - 1.0f, hi = mx;
  for (int it = 0; it < 40; ++it) {
    float mid = 0.5f * (lo + hi);
    float s = 0.f;
    #pragma unroll
    for (int j = 0; j < 16; ++j) {
      float d = zv[j] - mid;
      s += (d > 0.f) ? d : 0.f;
    }
    #pragma unroll
    for (int o = 32; o > 0; o >>= 1) s += __shfl_xor(s, o, 64);
    if ((tid & 63) == 0) sb[tid >> 6] = s;
    __syncthreads();
    s = sb[0] + sb[1] + sb[2] + sb[3];
    __syncthreads();
    if (s >= 1.0f) lo = mid; else hi = mid;   // uniform branch (s broadcast)
  }
  float mid = 0.5f * (lo + hi);

  // exact refinement: K = |{z > mid}|, tau = (sum_support - 1) / K
  float c = 0.f, s = 0.f;
  #pragma unroll
  for (int j = 0; j < 16; ++j) {
    if (zv[j] > mid) { c += 1.0f; s += zv[j]; }
  }
  #pragma unroll
  for (int o = 32; o > 0; o >>= 1) {
    c += __shfl_xor(c, o, 64);
    s += __shfl_xor(s, o, 64);
  }
  if ((tid & 63) == 0) { sb[tid >> 6] = c; sb2[tid >> 6] = s; }
  __syncthreads();
  c = sb[0] + sb[1] + sb[2] + sb[3];
  s = sb2[0] + sb2[1] + sb2[2] + sb2[3];
  float tau = (s - 1.0f) / fmaxf(c, 1.0f);

  // compact nonzeros (order irrelevant for the weighted sum)
  __shared__ int scnt;
  if (tid == 0) scnt = 0;
  __syncthreads();
  #pragma unroll
  for (int j = 0; j < 16; ++j) {
    float w = zv[j] - tau;
    if (w > 0.f) {
      int p = atomicAdd(&scnt, 1);
      idxl[(size_t)b * N_ + p] = j * 256 + tid;
      wl[(size_t)b * N_ + p]   = w;
    }
  }
  __syncthreads();
  if (tid == 0) cnt[b] = scnt;
}

// ---------------------------------------------------------------------------
// Kernel D: memory_vector[b,:] = sum over support of w * mem[b,n,:]
// grid 64, block 256. Support is ~90 rows/batch -> ~24 MB total read.
// ---------------------------------------------------------------------------
__global__ void k_memvec(const float* __restrict__ mem, const int* __restrict__ idxl,
                         const float* __restrict__ wl, const int* __restrict__ cnt,
                         float* __restrict__ cat) {
  int b = blockIdx.x, tid = threadIdx.x;
  int nnz = cnt[b];
  __shared__ int   sidx[256];
  __shared__ float sw[256];
  float4 acc = make_float4(0.f, 0.f, 0.f, 0.f);
  const float4* mb = (const float4*)mem + (size_t)b * N_ * 256;
  for (int c0 = 0; c0 < nnz; c0 += 256) {
    int c = nnz - c0; if (c > 256) c = 256;
    if (tid < c) {
      sidx[tid] = idxl[(size_t)b * N_ + c0 + tid];
      sw[tid]   = wl[(size_t)b * N_ + c0 + tid];
    }
    __syncthreads();
    #pragma unroll 8
    for (int i = 0; i < c; ++i) {
      float  w = sw[i];
      float4 r = mb[(size_t)sidx[i] * 256 + tid];
      acc.x += w * r.x; acc.y += w * r.y; acc.z += w * r.z; acc.w += w * r.w;
    }
    __syncthreads();
  }
  ((float4*)(cat + (size_t)b * DIN + D_))[tid] = acc;
}

// ---------------------------------------------------------------------------
// Kernel E: GEMM1 partials: hp[kt][m][n] = sum_{k in slice kt} cat[m,k]*W1[n,k]
// grid (64 n-tiles, 8 k-slices) = 512 blocks (2/CU), block 256.
// BM=BN=64, BK=16, K-slice 256.
// ---------------------------------------------------------------------------
__global__ void k_gemm1(const float* __restrict__ X, const float* __restrict__ W,
                        float* __restrict__ hp) {
  int nt = blockIdx.x, kt = blockIdx.y, tid = threadIdx.x;
  __shared__ float Xs[16][68];
  __shared__ float Ws[16][68];
  int row = tid >> 2, c4 = (tid & 3) * 4;       // loader coords
  int tm = (tid & 15) * 4, tn = (tid >> 4) * 4; // compute coords (4x4 tile)
  float acc[4][4] = {};
  const float* Xp = X + (size_t)row * DIN + c4;
  const float* Wp = W + ((size_t)nt * 64 + row) * DIN + c4;
  int kend = kt * 256 + 256;
  for (int k0 = kt * 256; k0 < kend; k0 += 16) {
    float4 xv = *(const float4*)(Xp + k0);
    float4 wv = *(const float4*)(Wp + k0);
    __syncthreads();
    Xs[c4+0][row] = xv.x; Xs[c4+1][row] = xv.y; Xs[c4+2][row] = xv.z; Xs[c4+3][row] = xv.w;
    Ws[c4+0][row] = wv.x; Ws[c4+1][row] = wv.y; Ws[c4+2][row] = wv.z; Ws[c4+3][row] = wv.w;
    __syncthreads();
    #pragma unroll
    for (int kk = 0; kk < 16; ++kk) {
      float a0 = Xs[kk][tm+0], a1 = Xs[kk][tm+1], a2 = Xs[kk][tm+2], a3 = Xs[kk][tm+3];
      float b0 = Ws[kk][tn+0], b1 = Ws[kk][tn+1], b2 = Ws[kk][tn+2], b3 = Ws[kk][tn+3];
      acc[0][0] += a0*b0; acc[0][1] += a0*b1; acc[0][2] += a0*b2; acc[0][3] += a0*b3;
      acc[1][0] += a1*b0; acc[1][1] += a1*b1; acc[1][2] += a1*b2; acc[1][3] += a1*b3;
      acc[2][0] += a2*b0; acc[2][1] += a2*b1; acc[2][2] += a2*b2; acc[2][3] += a2*b3;
      acc[3][0] += a3*b0; acc[3][1] += a3*b1; acc[3][2] += a3*b2; acc[3][3] += a3*b3;
    }
  }
  float* o = hp + ((size_t)kt * 64 + tm) * DHID + nt * 64 + tn;
  #pragma unroll
  for (int i = 0; i < 4; ++i)
    *(float4*)(o + (size_t)i * DHID) = make_float4(acc[i][0], acc[i][1], acc[i][2], acc[i][3]);
}

// ---------------------------------------------------------------------------
// Kernel F: h[m,k] = relu(b1[k] + sum_{p<8} hp[p][m][k])   [64, 4096]
// grid 256, block 256 (one float4 per thread)
// ---------------------------------------------------------------------------
__global__ void k_hrelu(const float* __restrict__ hp, const float* __restrict__ b1p,
                        float* __restrict__ h) {
  int flat4 = blockIdx.x * 256 + threadIdx.x;      // float4 index into [64*4096/4]
  int k4 = flat4 & 1023;                            // float4 index within row
  float4 acc = ((const float4*)b1p)[k4];
  #pragma unroll
  for (int p = 0; p < 8; ++p) {
    float4 v = ((const float4*)hp)[(size_t)p * 65536 + flat4];
    acc.x += v.x; acc.y += v.y; acc.z += v.z; acc.w += v.w;
  }
  acc.x = fmaxf(acc.x, 0.f); acc.y = fmaxf(acc.y, 0.f);
  acc.z = fmaxf(acc.z, 0.f); acc.w = fmaxf(acc.w, 0.f);
  ((float4*)h)[flat4] = acc;
}

// ---------------------------------------------------------------------------
// Kernel G: GEMM2 partials: op[kt][m][n] = sum_{k in slice} h[m,k]*W2[n,k]
// grid (16 n-tiles, 16 k-slices) = 256 blocks, block 256. K-slice 256.
// ---------------------------------------------------------------------------
__global__ void k_gemm2(const float* __restrict__ h, const float* __restrict__ W2,
                        float* __restrict__ op) {
  int nt = blockIdx.x, kt = blockIdx.y, tid = threadIdx.x;
  __shared__ float Xs[16][68];
  __shared__ float Ws[16][68];
  int row = tid >> 2, c4 = (tid & 3) * 4;
  int tm = (tid & 15) * 4, tn = (tid >> 4) * 4;
  int nbase = nt * 64;
  int n = nbase + row;
  float acc[4][4] = {};
  const float* Xp = h + (size_t)row * DHID + c4;
  const float* Wp = W2 + (size_t)n * DHID + c4;
  int kend = kt * 256 + 256;
  for (int k0 = kt * 256; k0 < kend; k0 += 16) {
    float4 xv = *(const float4*)(Xp + k0);
    float4 wv = make_float4(0.f, 0.f, 0.f, 0.f);
    if (n < OUT_N) wv = *(const float4*)(Wp + k0);
    __syncthreads();
    Xs[c4+0][row] = xv.x; Xs[c4+1][row] = xv.y; Xs[c4+2][row] = xv.z; Xs[c4+3][row] = xv.w;
    Ws[c4+0][row] = wv.x; Ws[c4+1][row] = wv.y; Ws[c4+2][row] = wv.z; Ws[c4+3][row] = wv.w;
    __syncthreads();
    #pragma unroll
    for (int kk = 0; kk < 16; ++kk) {
      float a0 = Xs[kk][tm+0], a1 = Xs[kk][tm+1], a2 = Xs[kk][tm+2], a3 = Xs[kk][tm+3];
      float b0 = Ws[kk][tn+0], b1 = Ws[kk][tn+1], b2 = Ws[kk][tn+2], b3 = Ws[kk][tn+3];
      acc[0][0] += a0*b0; acc[0][1] += a0*b1; acc[0][2] += a0*b2; acc[0][3] += a0*b3;
      acc[1][0] += a1*b0; acc[1][1] += a1*b1; acc[1][2] += a1*b2; acc[1][3] += a1*b3;
      acc[2][0] += a2*b0; acc[2][1] += a2*b1; acc[2][2] += a2*b2; acc[2][3] += a2*b3;
      acc[3][0] += a3*b0; acc[3][1] += a3*b1; acc[3][2] += a3*b2; acc[3][3] += a3*b3;
    }
  }
  // op layout: [16][64][1024] (N padded to 1024; cols >= 1000 unused)
  float* o = op + ((size_t)kt * 64 + tm) * 1024 + nbase + tn;
  #pragma unroll
  for (int i = 0; i < 4; ++i)
    *(float4*)(o + (size_t)i * 1024) = make_float4(acc[i][0], acc[i][1], acc[i][2], acc[i][3]);
}

// ---------------------------------------------------------------------------
// Kernel H: out[b,o] = b2[o] + sum_kt op[kt][b][o]
// grid (4, 64), block 256
// ---------------------------------------------------------------------------
__global__ void k_out(const float* __restrict__ op, const float* __restrict__ b2p,
                      float* __restrict__ out) {
  int o = blockIdx.x * 256 + threadIdx.x;
  int b = blockIdx.y;
  if (o >= OUT_N) return;
  float s = b2p[o];
  #pragma unroll
  for (int kt = 0; kt < 16; ++kt) s += op[((size_t)kt * 64 + b) * 1024 + o];
  out[(size_t)b * OUT_N + o] = s;
}

// ---------------------------------------------------------------------------
extern "C" void kernel_launch(void* const* d_in, const int* in_sizes, int n_in,
                              void* d_out, int out_size, void* d_ws, size_t ws_size,
                              hipStream_t stream) {
  const float* enc = (const float*)d_in[0];   // [64, 1024]
  const float* mem = (const float*)d_in[1];   // [64, 4096, 1024]
  const float* W1  = (const float*)d_in[2];   // [4096, 2048]
  const float* b1  = (const float*)d_in[3];   // [4096]
  const float* W2  = (const float*)d_in[4];   // [1000, 4096]
  const float* b2  = (const float*)d_in[5];   // [1000]
  float* out = (float*)d_out;                 // [64, 1000]

  // workspace layout (floats); everything fully written before read
  float* ws      = (float*)d_ws;
  float* inv_enc = ws;                               // 64
  int*   cnt     = (int*)(ws + 64);                  // 64
  float* z       = ws + 128;                         // 262144
  int*   idxl    = (int*)(ws + 128 + 262144);        // 262144
  float* wl      = ws + 128 + 2 * 262144;            // 262144
  float* cat     = ws + 128 + 3 * 262144;            // 131072  [64, 2048]
  float* hp      = cat + 131072;                     // 2097152 [8][64][4096]
  float* h       = hp + 2097152;                     // 262144  [64][4096]
  float* op      = h + 262144;                       // 1048576 [16][64][1024]

  k_prep     <<<dim3(64),      dim3(256), 0, stream>>>(enc, cat, inv_enc);
  k_cos      <<<dim3(65536),   dim3(256), 0, stream>>>(enc, mem, z);
  k_sparsemax<<<dim3(64),      dim3(256), 0, stream>>>(z, inv_enc, idxl, wl, cnt);
  k_memvec   <<<dim3(64),      dim3(256), 0, stream>>>(mem, idxl, wl, cnt, cat);
  k_gemm1    <<<dim3(64, 8),   dim3(256), 0, stream>>>(cat, W1, hp);
  k_hrelu    <<<dim3(256),     dim3(256), 0, stream>>>(hp, b1, h);
  k_gemm2    <<<dim3(16, 16),  dim3(256), 0, stream>>>(h, W2, op);
  k_out      <<<dim3(4, 64),   dim3(256), 0, stream>>>(op, b2, out);
}